// Round 7
// baseline (305.158 us; speedup 1.0000x reference)
//
#include <hip/hip_runtime.h>
#include <hip/hip_bf16.h>
#include <math.h>

// Problem constants (ConViT GPSA): B=16, N=576, D=1024, H=16, HD=64
#define B_ 16
#define N_ 576
#define D_ 1024
#define H_ 16
#define HD_ 64
#define BN_ (B_ * N_)   // 9216 rows
#define LOG2E 1.4426950408889634f

typedef __bf16 bf16x8 __attribute__((ext_vector_type(8)));
typedef __bf16 bf16x4 __attribute__((ext_vector_type(4)));
typedef float  f32x4  __attribute__((ext_vector_type(4)));

// ---------------------------------------------------------------------------
// cast fp32 -> bf16, 4 elems/thread
// ---------------------------------------------------------------------------
__global__ __launch_bounds__(256) void cast_bf16(
    const float* __restrict__ in, __bf16* __restrict__ out)
{
    size_t i = ((size_t)blockIdx.x * 256 + threadIdx.x) * 4;
    float4 v = *(const float4*)&in[i];
    bf16x4 o;
    o.x = (__bf16)v.x; o.y = (__bf16)v.y; o.z = (__bf16)v.z; o.w = (__bf16)v.w;
    *(bf16x4*)&out[i] = o;
}

// ---------------------------------------------------------------------------
// transpose + cast: W[K,N] fp32 -> Wt[N,K] bf16. 64x64 tiles, 256 threads.
// ---------------------------------------------------------------------------
__global__ __launch_bounds__(256) void transpose_cast(
    const float* __restrict__ W, __bf16* __restrict__ Wt, int K, int N)
{
    __shared__ float t[64][65];
    const int tid = threadIdx.x;
    const int k0 = blockIdx.y * 64, n0 = blockIdx.x * 64;
    const int r = tid >> 4, c4 = (tid & 15) << 2;
#pragma unroll
    for (int s = 0; s < 4; ++s) {
        int rr = r + (s << 4);
        float4 w = *(const float4*)&W[(size_t)(k0 + rr) * N + n0 + c4];
        t[rr][c4] = w.x; t[rr][c4 + 1] = w.y; t[rr][c4 + 2] = w.z; t[rr][c4 + 3] = w.w;
    }
    __syncthreads();
#pragma unroll
    for (int s = 0; s < 4; ++s) {
        int rr = r + (s << 4);
        bf16x4 o;
        o.x = (__bf16)t[c4 + 0][rr]; o.y = (__bf16)t[c4 + 1][rr];
        o.z = (__bf16)t[c4 + 2][rr]; o.w = (__bf16)t[c4 + 3][rr];
        *(bf16x4*)&Wt[(size_t)(n0 + rr) * K + k0 + c4] = o;
    }
}

// ---------------------------------------------------------------------------
// 256x256 8-phase deep-pipelined bf16 MFMA GEMM (T1-T5), K=1024.
// C[M,N] = A[M,K] @ Bt[N,K]^T (+bias). 512 thr = 8 waves (2M x 4N), per-wave
// 128x64 out. LDS 2-buf x (A 256x64 + B 256x64) = 128 KiB, chunk-XOR swizzle
// (phys16B = logical ^ (row&7)), pre-swizzled global src + linear gll dest.
// Schedule = R3-proven ITER: per phase {1 stage-unit issue; vmcnt(4);
// lgkmcnt(0); s_barrier; frag ds_reads; 16 MFMA}. No vmcnt(0) in main loop.
// Tile order: ROW-MAJOR (R3-proven, FETCH 61.5 MB); R6 measured column-major
// at FETCH 117 MB / +8 us (A >> B so n-stripe walking re-streams all of A).
// Stage units: A0 = A rows {0-63,128-191}, A1 = +64;
//              B0 = Bt rows {0-31,64-95,128-159,192-223}, B1 = +32.
// OUTMODE: 0 = fp32 C[M,N]+bias; 3 = fused qk|v split (see launch).
// ---------------------------------------------------------------------------
template<int OUTMODE>
__global__ __launch_bounds__(512, 2) void gemm256(
    const __bf16* __restrict__ A, const __bf16* __restrict__ Bt,
    const float* __restrict__ bias, void* __restrict__ Cp, void* __restrict__ Cp2,
    int M, int N, int nbn)
{
    __shared__ __bf16 As[2][256 * 64];
    __shared__ __bf16 Bs[2][256 * 64];

    const int tid = threadIdx.x;
    const int lane = tid & 63, wave = tid >> 6;
    const int fr = lane & 15, quad = lane >> 4;

    // XCD-aware block swizzle (grid % 8 == 0 for both shapes)
    const int nwg = gridDim.x;
    const int wg = ((int)blockIdx.x & 7) * (nwg >> 3) + ((int)blockIdx.x >> 3);
    const int m0 = (wg / nbn) * 256;
    const int n0 = (wg % nbn) * 256;

    const int wm = (wave >> 2) * 128;
    const int wn = (wave & 3) * 64;

    // --- staging invariants: per-rep global offsets (pre-swizzled) + LDS dests
    int offA[2], offB[2], dA[2], dB[2];
#pragma unroll
    for (int r = 0; r < 2; ++r) {
        int rl = r * 64 + (tid >> 3);          // 16B-slot row index within unit
        int pc = tid & 7;                      // phys chunk
        int l  = pc ^ (rl & 7);                // logical chunk (pre-swizzle)
        int rowA = (rl & 63) | ((rl & 64) << 1);
        int rowB = (rl & 31) + ((rl >> 5) << 6);
        offA[r] = (m0 + rowA) * 1024 + l * 8;
        offB[r] = (n0 + rowB) * 1024 + l * 8;
        int rlb = r * 64 + wave * 8;           // wave-uniform dest base
        int rowAb = (rlb & 63) | ((rlb & 64) << 1);
        int rowBb = (rlb & 31) + ((rlb >> 5) << 6);
        dA[r] = rowAb * 64;
        dB[r] = rowBb * 64;
    }

    const int cA0 = (quad ^ (fr & 7)) * 8;         // kslice0 chunk (swizzled)
    const int cA1 = ((4 + quad) ^ (fr & 7)) * 8;   // kslice1 chunk

    f32x4 acc[8][4];
#pragma unroll
    for (int i = 0; i < 8; ++i)
#pragma unroll
        for (int j = 0; j < 4; ++j)
            acc[i][j] = (f32x4){0.f, 0.f, 0.f, 0.f};

    bf16x8 af[2][4];        // current A-half frags [kslice][i]
    bf16x8 bfr[2][2][2];    // whole-tile B frags [nhalf][kslice][j]

#define GLL16(src, dst) __builtin_amdgcn_global_load_lds( \
    (const __attribute__((address_space(1))) void*)(src), \
    (__attribute__((address_space(3))) void*)(dst), 16, 0, 0)

#define ISSUE_A(U, BUF, KOFF) { \
    GLL16(A + offA[0] + (U) * 65536 + (KOFF), &As[BUF][dA[0] + (U) * 4096]); \
    GLL16(A + offA[1] + (U) * 65536 + (KOFF), &As[BUF][dA[1] + (U) * 4096]); }
#define ISSUE_B(U, BUF, KOFF) { \
    GLL16(Bt + offB[0] + (U) * 32768 + (KOFF), &Bs[BUF][dB[0] + (U) * 2048]); \
    GLL16(Bt + offB[1] + (U) * 32768 + (KOFF), &Bs[BUF][dB[1] + (U) * 2048]); }

#define READ_A(BUF, MH) { \
    const __bf16* _p = &As[BUF][(wm + (MH) * 64 + fr) * 64]; \
    _Pragma("unroll") for (int i = 0; i < 4; ++i) { \
        af[0][i] = *(const bf16x8*)&_p[i * 1024 + cA0]; \
        af[1][i] = *(const bf16x8*)&_p[i * 1024 + cA1]; } }

#define READ_B(BUF, NH) { \
    const __bf16* _p = &Bs[BUF][(wn + (NH) * 32 + fr) * 64]; \
    _Pragma("unroll") for (int j = 0; j < 2; ++j) { \
        bfr[NH][0][j] = *(const bf16x8*)&_p[j * 1024 + cA0]; \
        bfr[NH][1][j] = *(const bf16x8*)&_p[j * 1024 + cA1]; } }

#define MFMAQ(MH, NH) { \
    __builtin_amdgcn_s_setprio(1); \
    _Pragma("unroll") for (int i = 0; i < 4; ++i) \
    _Pragma("unroll") for (int j = 0; j < 2; ++j) { \
        f32x4 c = acc[(MH) * 4 + i][(NH) * 2 + j]; \
        c = __builtin_amdgcn_mfma_f32_16x16x32_bf16(af[0][i], bfr[NH][0][j], c, 0, 0, 0); \
        c = __builtin_amdgcn_mfma_f32_16x16x32_bf16(af[1][i], bfr[NH][1][j], c, 0, 0, 0); \
        acc[(MH) * 4 + i][(NH) * 2 + j] = c; } \
    __builtin_amdgcn_s_setprio(0); }

#define WAITV(N) asm volatile("s_waitcnt vmcnt(" #N ")" ::: "memory")
// lgkm drain before EVERY barrier: guarantees this wave's LDS reads are
// complete before it crosses -- closes the DMA-overwrite WAR race.
#define BARL() { asm volatile("s_waitcnt lgkmcnt(0)" ::: "memory"); \
                 asm volatile("s_barrier" ::: "memory"); }

#define ITER(LAST) { \
    /* p1 (0,0) */ ISSUE_A(0, 1, kodd); WAITV(4); BARL(); READ_A(0, 0); READ_B(0, 0); MFMAQ(0, 0); \
    /* p2 (0,1) */ ISSUE_B(0, 1, kodd); WAITV(4); BARL(); READ_B(0, 1); MFMAQ(0, 1); \
    /* p3 (1,1) */ ISSUE_A(1, 1, kodd); WAITV(4); BARL(); READ_A(0, 1); MFMAQ(1, 1); \
    /* p4 (1,0) */ ISSUE_B(1, 1, kodd); WAITV(4); BARL(); MFMAQ(1, 0); \
    /* p5 (0,0) */ if (!(LAST)) { ISSUE_A(0, 0, keven); } WAITV(4); BARL(); READ_A(1, 0); READ_B(1, 0); MFMAQ(0, 0); \
    /* p6 (0,1) */ if (!(LAST)) { ISSUE_B(0, 0, keven); WAITV(4); } else { WAITV(0); } BARL(); READ_B(1, 1); MFMAQ(0, 1); \
    /* p7 (1,1) */ if (!(LAST)) { ISSUE_A(1, 0, keven); WAITV(4); } BARL(); READ_A(1, 1); MFMAQ(1, 1); \
    /* p8 (1,0) */ if (!(LAST)) { ISSUE_B(1, 0, keven); WAITV(4); } BARL(); MFMAQ(1, 0); }

    // prologue: stage tile0 -> buf0 (4 units)
    ISSUE_A(0, 0, 0); ISSUE_B(0, 0, 0); ISSUE_A(1, 0, 0); ISSUE_B(1, 0, 0);

#pragma unroll 1
    for (int it = 0; it < 7; ++it) {
        const int kodd  = it * 128 + 64;   // odd tile (2it+1) k-offset, -> buf1
        const int keven = it * 128 + 128;  // even tile (2it+2) k-offset, -> buf0
        ITER(0);
    }
    {
        const int kodd  = 7 * 128 + 64;    // tile 15 -> buf1
        const int keven = 0;               // unused
        ITER(1);
    }

#undef ITER
#undef WAITV
#undef BARL
#undef MFMAQ
#undef READ_B
#undef READ_A
#undef ISSUE_B
#undef ISSUE_A
#undef GLL16

    // epilogue: C/D layout col=lane&15 (n-side), row=quad*4+reg (m-side)
    const int colb = n0 + wn + fr;
    const int rowb = m0 + wm + quad * 4;
#pragma unroll
    for (int j = 0; j < 4; ++j) {
        int col = colb + j * 16;
        float bv = (OUTMODE == 0 && bias) ? bias[col] : 0.0f;
#pragma unroll
        for (int i = 0; i < 8; ++i) {
            int row = rowb + i * 16;
            if (OUTMODE == 3) {
                if (col < 2048) {       // block-uniform (n0 mult of 256)
#pragma unroll
                    for (int t = 0; t < 4; ++t)
                        ((__bf16*)Cp)[(size_t)(row + t) * 2048 + col] = (__bf16)acc[i][j][t];
                } else {
                    int bb = row / 576;
                    int ml = row - bb * 576;   // ml%4==0, never crosses batch
                    bf16x4 o4;
#pragma unroll
                    for (int t = 0; t < 4; ++t) o4[t] = (__bf16)acc[i][j][t];
                    *(bf16x4*)&((__bf16*)Cp2)[((size_t)bb * 1024 + (col - 2048)) * 576 + ml] = o4;
                }
            } else {
#pragma unroll
                for (int t = 0; t < 4; ++t)
                    ((float*)Cp)[(size_t)(row + t) * N + col] = acc[i][j][t] + bv;
            }
        }
    }
}

// ---------------------------------------------------------------------------
// pos materialization: Pp[h][n][m] = g_h * softmax_m(pos_logits)  (bf16)
// ---------------------------------------------------------------------------
__global__ __launch_bounds__(64) void pos_mat(
    const float* __restrict__ W_pos, const float* __restrict__ gating,
    __bf16* __restrict__ Pp)
{
    const int h = blockIdx.x / N_;
    const int n = blockIdx.x % N_;
    const int lane = threadIdx.x;
    const float w0 = W_pos[h] * LOG2E, w1 = W_pos[H_ + h] * LOG2E,
                w2 = W_pos[2 * H_ + h] * LOG2E;
    const float rx = (float)(n % 24), ry = (float)(n / 24);
    float l2[9];
    float mx = -1e30f;
#pragma unroll
    for (int i = 0; i < 9; ++i) {
        int m = lane + (i << 6);
        float cx = (float)(m % 24), cy = (float)(m / 24);
        float dx = cx - rx, dy = cy - ry;
        float l = fmaf(w2, fmaf(dx, dx, dy * dy), fmaf(w0, dx, w1 * dy));
        l2[i] = l;
        mx = fmaxf(mx, l);
    }
#pragma unroll
    for (int off = 32; off; off >>= 1) mx = fmaxf(mx, __shfl_xor(mx, off, 64));
    float sum = 0.f;
#pragma unroll
    for (int i = 0; i < 9; ++i) sum += __builtin_amdgcn_exp2f(l2[i] - mx);
#pragma unroll
    for (int off = 32; off; off >>= 1) sum += __shfl_xor(sum, off, 64);
    float g = 1.f / (1.f + __expf(-gating[h]));
    float c = __log2f(g) - mx - __log2f(sum);
    __bf16* row = Pp + (size_t)(h * N_ + n) * N_;
#pragma unroll
    for (int i = 0; i < 9; ++i)
        row[(i << 6) + lane] = (__bf16)__builtin_amdgcn_exp2f(l2[i] + c);
}

// ---------------------------------------------------------------------------
// MFMA gated attention v6. Block = (b,h), 768 threads = 12 waves (3/SIMD --
// up from 8 waves/2-per-SIMD: attn is latency-bound at Occ 20%, and 36
// q-tiles / 12 waves = 3.0 exact so the 8-wave 5/4 imbalance disappears;
// grid 256 blocks = 256 CUs, no tail). K and V^T staged once into LDS;
// content-only softmax in registers; positional part via precomputed bf16
// fragments (Pp) fed to a second PV MFMA per kb.
// Scratch stride 40 bf16 (16B-aligned; cols used <= 32, rows 16).
// LDS: K 73728 + V 73728 + Sc 12*16*40*2 = 15360 -> 162816 <= 163840.
// ---------------------------------------------------------------------------
__global__ __launch_bounds__(768, 3) void attn_mfma3(
    const __bf16* __restrict__ qk, const __bf16* __restrict__ vt,
    const __bf16* __restrict__ Pp, const float* __restrict__ gating,
    __bf16* __restrict__ ao)
{
    __shared__ __bf16 Ks[N_ * HD_];        // [n][d], phys chunk = logical ^ (n&7)
    __shared__ __bf16 Vs[HD_ * N_];        // [d][m], phys = (l&~7)|((l&7)^(d&7))
    __shared__ __bf16 Sc[12 * 16 * 40];    // per-wave scratch [16][40]

    const int bid = blockIdx.x;
    const int h = bid & 15, b = bid >> 4;
    const int tid = threadIdx.x;
    const int lane = tid & 63, wave = tid >> 6;   // 0..11
    const int fr = lane & 15, quad = lane >> 4;

    const __bf16* qbase = qk + (size_t)b * N_ * (2 * D_) + h * HD_;
    const __bf16* kgl   = qbase + D_;
    const __bf16* vgl   = vt + (size_t)(b * H_ + h) * HD_ * N_;

    // ---- stage K [576x64] and V^T [64x576] into LDS (swizzled): 4608 chunks
#pragma unroll 3
    for (int it = 0; it < 6; ++it) {
        int s = it * 768 + tid;
        int r = s >> 3, p = s & 7;
        int l = p ^ (r & 7);
        __builtin_amdgcn_global_load_lds(
            (const __attribute__((address_space(1))) void*)(kgl + (size_t)r * (2 * D_) + l * 8),
            (__attribute__((address_space(3))) void*)&Ks[(size_t)(it * 768 + wave * 64) * 8],
            16, 0, 0);
        int d = s / 72, pv = s - d * 72;
        int lv = (pv & ~7) | ((pv & 7) ^ (d & 7));
        __builtin_amdgcn_global_load_lds(
            (const __attribute__((address_space(1))) void*)(vgl + (size_t)d * N_ + lv * 8),
            (__attribute__((address_space(3))) void*)&Vs[(size_t)(it * 768 + wave * 64) * 8],
            16, 0, 0);
    }
    __syncthreads();

    const float g   = 1.f / (1.f + __expf(-gating[h]));
    const float omg = 1.f - g;
    const float kk = 0.125f * LOG2E;

    __bf16* sw = &Sc[wave * 16 * 40];

    for (int tt = wave; tt < 36; tt += 12) {
        const int n0 = tt * 16;

        const __bf16* qp = qbase + (size_t)(n0 + fr) * (2 * D_) + quad * 8;
        bf16x8 qf0 = *(const bf16x8*)qp;
        bf16x8 qf1 = *(const bf16x8*)(qp + 32);

        const __bf16* pprow = Pp + ((size_t)h * N_ + n0 + fr) * N_ + quad * 8;

        f32x4 S[36];
#pragma unroll
        for (int ct = 0; ct < 36; ++ct) {
            int row = ct * 16 + fr;
            int p0 = quad ^ (row & 7);
            int p1 = (4 + quad) ^ (row & 7);
            bf16x8 k0 = *(const bf16x8*)&Ks[row * 64 + p0 * 8];
            bf16x8 k1 = *(const bf16x8*)&Ks[row * 64 + p1 * 8];
            f32x4 a = (f32x4){0.f, 0.f, 0.f, 0.f};
            a = __builtin_amdgcn_mfma_f32_16x16x32_bf16(qf0, k0, a, 0, 0, 0);
            a = __builtin_amdgcn_mfma_f32_16x16x32_bf16(qf1, k1, a, 0, 0, 0);
            S[ct] = a;
        }

        float inv[4];
#pragma unroll
        for (int t = 0; t < 4; ++t) {
            float mt[18];
#pragma unroll
            for (int i = 0; i < 18; ++i) mt[i] = fmaxf(S[i][t], S[i + 18][t]);
#pragma unroll
            for (int i = 0; i < 9; ++i) mt[i] = fmaxf(mt[i], mt[i + 9]);
            float m = fmaxf(fmaxf(fmaxf(mt[0], mt[1]), fmaxf(mt[2], mt[3])),
                            fmaxf(fmaxf(fmaxf(mt[4], mt[5]), fmaxf(mt[6], mt[7])), mt[8]));
            m = fmaxf(m, __shfl_xor(m, 1, 16));
            m = fmaxf(m, __shfl_xor(m, 2, 16));
            m = fmaxf(m, __shfl_xor(m, 4, 16));
            m = fmaxf(m, __shfl_xor(m, 8, 16));
            float km = kk * m;
            float s0 = 0.f, s1 = 0.f, s2 = 0.f, s3 = 0.f;
#pragma unroll
            for (int ct = 0; ct < 36; ++ct) {
                float e = __builtin_amdgcn_exp2f(fmaf(kk, S[ct][t], -km));
                S[ct][t] = e;
                if ((ct & 3) == 0)      s0 += e;
                else if ((ct & 3) == 1) s1 += e;
                else if ((ct & 3) == 2) s2 += e;
                else                    s3 += e;
            }
            float s = (s0 + s1) + (s2 + s3);
            s += __shfl_xor(s, 1, 16);
            s += __shfl_xor(s, 2, 16);
            s += __shfl_xor(s, 4, 16);
            s += __shfl_xor(s, 8, 16);
            inv[t] = omg / s;
        }

        f32x4 O[4];
#pragma unroll
        for (int dt = 0; dt < 4; ++dt) O[dt] = (f32x4){0.f, 0.f, 0.f, 0.f};
#pragma unroll
        for (int kb = 0; kb < 18; ++kb) {
            bf16x8 posf = *(const bf16x8*)(pprow + kb * 32);
#pragma unroll
            for (int ctl = 0; ctl < 2; ++ctl) {
                int ct = 2 * kb + ctl;
#pragma unroll
                for (int t = 0; t < 4; ++t) {
                    float pval = S[ct][t] * inv[t];
                    sw[(quad * 4 + t) * 40 + ctl * 16 + fr] = (__bf16)pval;
                }
            }
            bf16x8 pf = *(const bf16x8*)&sw[fr * 40 + quad * 8];
#pragma unroll
            for (int dt = 0; dt < 4; ++dt) {
                int d = dt * 16 + fr;
                int l = kb * 4 + quad;
                int p = (l & ~7) | ((l & 7) ^ (d & 7));
                bf16x8 vf = *(const bf16x8*)&Vs[d * 576 + p * 8];
                O[dt] = __builtin_amdgcn_mfma_f32_16x16x32_bf16(vf, pf,   O[dt], 0, 0, 0);
                O[dt] = __builtin_amdgcn_mfma_f32_16x16x32_bf16(vf, posf, O[dt], 0, 0, 0);
            }
        }

        asm volatile("s_waitcnt lgkmcnt(0)" ::: "memory");
#pragma unroll
        for (int ps = 0; ps < 2; ++ps) {
#pragma unroll
            for (int dh = 0; dh < 2; ++dh) {
                int dt = 2 * ps + dh;
                bf16x4 o4;
#pragma unroll
                for (int t = 0; t < 4; ++t) o4[t] = (__bf16)O[dt][t];
                *(bf16x4*)&sw[fr * 40 + dh * 16 + quad * 4] = o4;
            }
            asm volatile("s_waitcnt lgkmcnt(0)" ::: "memory");
            {
                int row = lane >> 2;
                int off = (lane & 3) * 8;
                bf16x8 ov = *(const bf16x8*)&sw[row * 40 + off];
                *(bf16x8*)&ao[((size_t)b * N_ + n0 + row) * D_ + h * HD_ + ps * 32 + off] = ov;
            }
            asm volatile("s_waitcnt lgkmcnt(0)" ::: "memory");
        }
    }
}

// ---------------------------------------------------------------------------
extern "C" void kernel_launch(void* const* d_in, const int* in_sizes, int n_in,
                              void* d_out, int out_size, void* d_ws, size_t ws_size,
                              hipStream_t stream)
{
    const float* x      = (const float*)d_in[0];
    const float* W_qk   = (const float*)d_in[1];
    const float* W_v    = (const float*)d_in[2];
    const float* W_proj = (const float*)d_in[3];
    const float* b_proj = (const float*)d_in[4];
    const float* W_pos  = (const float*)d_in[5];
    const float* b_pos  = (const float*)d_in[6];   // unused: cancels in softmax
    const float* gating = (const float*)d_in[7];
    const float* rel    = (const float*)d_in[8];   // unused: computed on the fly
    (void)b_pos; (void)rel;
    float* out = (float*)d_out;

    // workspace carve (~114 MB)
    char* p = (char*)d_ws;
    __bf16* xb    = (__bf16*)p;  p += (size_t)BN_ * D_ * 2;            // 18.9 MB
    __bf16* wqkvt = (__bf16*)p;  p += (size_t)(3 * D_) * D_ * 2;       //  6.3 MB
    __bf16* wpt   = (__bf16*)p;  p += (size_t)D_ * D_ * 2;             //  2.1 MB
    __bf16* qkb   = (__bf16*)p;  p += (size_t)BN_ * (2 * D_) * 2;      // 37.7 MB
    __bf16* vt    = (__bf16*)p;  p += (size_t)BN_ * D_ * 2;            // 18.9 MB [b,h,d,m]
    __bf16* aob   = (__bf16*)p;  p += (size_t)BN_ * D_ * 2;            // 18.9 MB
    __bf16* Pp    = (__bf16*)p;                                        // 10.6 MB [h,n,m]

    cast_bf16<<<(BN_ * D_) / 1024, 256, 0, stream>>>(x, xb);
    // concat [W_qk | W_v]^T into wqkvt[3072][1024]
    transpose_cast<<<dim3((2 * D_) / 64, D_ / 64), 256, 0, stream>>>(W_qk, wqkvt, D_, 2 * D_);
    transpose_cast<<<dim3(D_ / 64, D_ / 64), 256, 0, stream>>>(W_v, wqkvt + (size_t)2 * D_ * D_, D_, D_);
    transpose_cast<<<dim3(D_ / 64, D_ / 64), 256, 0, stream>>>(W_proj, wpt, D_, D_);

    // fused qk|v GEMM: N=3072; cols<2048 -> qkb, cols>=2048 -> vt (transposed)
    gemm256<3><<<dim3((BN_ / 256) * (3 * D_ / 256)), 512, 0, stream>>>(
        xb, wqkvt, nullptr, qkb, vt, BN_, 3 * D_, 3 * D_ / 256);
    pos_mat<<<H_ * N_, 64, 0, stream>>>(W_pos, gating, Pp);
    attn_mfma3<<<B_ * H_, 768, 0, stream>>>(qkb, vt, Pp, gating, aob);
    gemm256<0><<<dim3((BN_ / 256) * (D_ / 256)), 512, 0, stream>>>(
        aob, wpt, b_proj, out, nullptr, BN_, D_, D_ / 256);
}

// Round 8
// 282.525 us; speedup vs baseline: 1.0801x; 1.0801x over previous
//
#include <hip/hip_runtime.h>
#include <hip/hip_bf16.h>
#include <math.h>

// Problem constants (ConViT GPSA): B=16, N=576, D=1024, H=16, HD=64
#define B_ 16
#define N_ 576
#define D_ 1024
#define H_ 16
#define HD_ 64
#define BN_ (B_ * N_)   // 9216 rows
#define LOG2E 1.4426950408889634f

typedef __bf16 bf16x8 __attribute__((ext_vector_type(8)));
typedef __bf16 bf16x4 __attribute__((ext_vector_type(4)));
typedef float  f32x4  __attribute__((ext_vector_type(4)));

// ---------------------------------------------------------------------------
// fused prep kernel (one launch instead of 5):
//   region 0 (blocks 0..9215):      cast x fp32 -> xb bf16 (4 elem/thread)
//   region 1 (blocks 9216..10239):  transpose+cast W_qk|W_v -> wqkvt, W_proj -> wpt
//   region 2 (blocks 10240..12543): pos softmax -> Pp[h][n][m] bf16 (4 n/block)
// Region switch is block-uniform; 256 threads everywhere. The memory-bound
// cast co-schedules with the exp2-heavy pos region across CUs.
// ---------------------------------------------------------------------------
__global__ __launch_bounds__(256) void prep(
    const float* __restrict__ x, const float* __restrict__ W_qk,
    const float* __restrict__ W_v, const float* __restrict__ W_proj,
    const float* __restrict__ W_pos, const float* __restrict__ gating,
    __bf16* __restrict__ xb, __bf16* __restrict__ wqkvt,
    __bf16* __restrict__ wpt, __bf16* __restrict__ Pp)
{
    __shared__ float t[64][65];
    const int bid = blockIdx.x;
    const int tid = threadIdx.x;

    if (bid < 9216) {
        // ---- cast fp32 -> bf16
        size_t i = ((size_t)bid * 256 + tid) * 4;
        float4 v = *(const float4*)&x[i];
        bf16x4 o;
        o.x = (__bf16)v.x; o.y = (__bf16)v.y; o.z = (__bf16)v.z; o.w = (__bf16)v.w;
        *(bf16x4*)&xb[i] = o;
    } else if (bid < 10240) {
        // ---- transpose+cast 64x64 tile
        int idx = bid - 9216;
        const float* W; __bf16* Wt; int N, bx, by;
        if (idx < 512)      { W = W_qk;   Wt = wqkvt;                          N = 2 * D_; bx = idx & 31; by = idx >> 5; }
        else if (idx < 768) { idx -= 512; W = W_v;    Wt = wqkvt + (size_t)2 * D_ * D_; N = D_; bx = idx & 15; by = idx >> 4; }
        else                { idx -= 768; W = W_proj; Wt = wpt;                N = D_;     bx = idx & 15; by = idx >> 4; }
        const int k0 = by * 64, n0 = bx * 64;
        const int r = tid >> 4, c4 = (tid & 15) << 2;
#pragma unroll
        for (int s = 0; s < 4; ++s) {
            int rr = r + (s << 4);
            float4 w = *(const float4*)&W[(size_t)(k0 + rr) * N + n0 + c4];
            t[rr][c4] = w.x; t[rr][c4 + 1] = w.y; t[rr][c4 + 2] = w.z; t[rr][c4 + 3] = w.w;
        }
        __syncthreads();
#pragma unroll
        for (int s = 0; s < 4; ++s) {
            int rr = r + (s << 4);
            bf16x4 o;
            o.x = (__bf16)t[c4 + 0][rr]; o.y = (__bf16)t[c4 + 1][rr];
            o.z = (__bf16)t[c4 + 2][rr]; o.w = (__bf16)t[c4 + 3][rr];
            *(bf16x4*)&Wt[(size_t)(n0 + rr) * D_ + k0 + c4] = o;
        }
    } else {
        // ---- pos: Pp[h][n][m] = g_h * softmax_m(pos_logits), one n per wave
        int flat = (bid - 10240) * 4 + (tid >> 6);
        int h = flat / N_, n = flat % N_;
        int lane = tid & 63;
        const float w0 = W_pos[h] * LOG2E, w1 = W_pos[H_ + h] * LOG2E,
                    w2 = W_pos[2 * H_ + h] * LOG2E;
        const float rx = (float)(n % 24), ry = (float)(n / 24);
        float l2[9];
        float mx = -1e30f;
#pragma unroll
        for (int i = 0; i < 9; ++i) {
            int m = lane + (i << 6);
            float cx = (float)(m % 24), cy = (float)(m / 24);
            float dx = cx - rx, dy = cy - ry;
            float l = fmaf(w2, fmaf(dx, dx, dy * dy), fmaf(w0, dx, w1 * dy));
            l2[i] = l;
            mx = fmaxf(mx, l);
        }
#pragma unroll
        for (int off = 32; off; off >>= 1) mx = fmaxf(mx, __shfl_xor(mx, off, 64));
        float sum = 0.f;
#pragma unroll
        for (int i = 0; i < 9; ++i) sum += __builtin_amdgcn_exp2f(l2[i] - mx);
#pragma unroll
        for (int off = 32; off; off >>= 1) sum += __shfl_xor(sum, off, 64);
        float g = 1.f / (1.f + __expf(-gating[h]));
        float c = __log2f(g) - mx - __log2f(sum);
        __bf16* row = Pp + (size_t)(h * N_ + n) * N_;
#pragma unroll
        for (int i = 0; i < 9; ++i)
            row[(i << 6) + lane] = (__bf16)__builtin_amdgcn_exp2f(l2[i] + c);
    }
}

// ---------------------------------------------------------------------------
// 256x256 8-phase deep-pipelined bf16 MFMA GEMM (T1-T5), K=1024.
// C[M,N] = A[M,K] @ Bt[N,K]^T (+bias). 512 thr = 8 waves (2M x 4N), per-wave
// 128x64 out. LDS 2-buf x (A 256x64 + B 256x64) = 128 KiB, chunk-XOR swizzle
// (phys16B = logical ^ (row&7)), pre-swizzled global src + linear gll dest.
// Schedule = R3-proven ITER: per phase {1 stage-unit issue; vmcnt(4);
// lgkmcnt(0); s_barrier; frag ds_reads; 16 MFMA}. No vmcnt(0) in main loop.
// Tile order: ROW-MAJOR (R3-proven, FETCH 61.5 MB); R6 measured column-major
// at FETCH 117 MB / +8 us (A >> B so n-stripe walking re-streams all of A).
// OUTMODE: 0 = fp32 C[M,N]+bias; 3 = fused qk|v split (see launch).
// ---------------------------------------------------------------------------
template<int OUTMODE>
__global__ __launch_bounds__(512, 2) void gemm256(
    const __bf16* __restrict__ A, const __bf16* __restrict__ Bt,
    const float* __restrict__ bias, void* __restrict__ Cp, void* __restrict__ Cp2,
    int M, int N, int nbn)
{
    __shared__ __bf16 As[2][256 * 64];
    __shared__ __bf16 Bs[2][256 * 64];

    const int tid = threadIdx.x;
    const int lane = tid & 63, wave = tid >> 6;
    const int fr = lane & 15, quad = lane >> 4;

    // XCD-aware block swizzle (grid % 8 == 0 for both shapes)
    const int nwg = gridDim.x;
    const int wg = ((int)blockIdx.x & 7) * (nwg >> 3) + ((int)blockIdx.x >> 3);
    const int m0 = (wg / nbn) * 256;
    const int n0 = (wg % nbn) * 256;

    const int wm = (wave >> 2) * 128;
    const int wn = (wave & 3) * 64;

    // --- staging invariants: per-rep global offsets (pre-swizzled) + LDS dests
    int offA[2], offB[2], dA[2], dB[2];
#pragma unroll
    for (int r = 0; r < 2; ++r) {
        int rl = r * 64 + (tid >> 3);          // 16B-slot row index within unit
        int pc = tid & 7;                      // phys chunk
        int l  = pc ^ (rl & 7);                // logical chunk (pre-swizzle)
        int rowA = (rl & 63) | ((rl & 64) << 1);
        int rowB = (rl & 31) + ((rl >> 5) << 6);
        offA[r] = (m0 + rowA) * 1024 + l * 8;
        offB[r] = (n0 + rowB) * 1024 + l * 8;
        int rlb = r * 64 + wave * 8;           // wave-uniform dest base
        int rowAb = (rlb & 63) | ((rlb & 64) << 1);
        int rowBb = (rlb & 31) + ((rlb >> 5) << 6);
        dA[r] = rowAb * 64;
        dB[r] = rowBb * 64;
    }

    const int cA0 = (quad ^ (fr & 7)) * 8;         // kslice0 chunk (swizzled)
    const int cA1 = ((4 + quad) ^ (fr & 7)) * 8;   // kslice1 chunk

    f32x4 acc[8][4];
#pragma unroll
    for (int i = 0; i < 8; ++i)
#pragma unroll
        for (int j = 0; j < 4; ++j)
            acc[i][j] = (f32x4){0.f, 0.f, 0.f, 0.f};

    bf16x8 af[2][4];        // current A-half frags [kslice][i]
    bf16x8 bfr[2][2][2];    // whole-tile B frags [nhalf][kslice][j]

#define GLL16(src, dst) __builtin_amdgcn_global_load_lds( \
    (const __attribute__((address_space(1))) void*)(src), \
    (__attribute__((address_space(3))) void*)(dst), 16, 0, 0)

#define ISSUE_A(U, BUF, KOFF) { \
    GLL16(A + offA[0] + (U) * 65536 + (KOFF), &As[BUF][dA[0] + (U) * 4096]); \
    GLL16(A + offA[1] + (U) * 65536 + (KOFF), &As[BUF][dA[1] + (U) * 4096]); }
#define ISSUE_B(U, BUF, KOFF) { \
    GLL16(Bt + offB[0] + (U) * 32768 + (KOFF), &Bs[BUF][dB[0] + (U) * 2048]); \
    GLL16(Bt + offB[1] + (U) * 32768 + (KOFF), &Bs[BUF][dB[1] + (U) * 2048]); }

#define READ_A(BUF, MH) { \
    const __bf16* _p = &As[BUF][(wm + (MH) * 64 + fr) * 64]; \
    _Pragma("unroll") for (int i = 0; i < 4; ++i) { \
        af[0][i] = *(const bf16x8*)&_p[i * 1024 + cA0]; \
        af[1][i] = *(const bf16x8*)&_p[i * 1024 + cA1]; } }

#define READ_B(BUF, NH) { \
    const __bf16* _p = &Bs[BUF][(wn + (NH) * 32 + fr) * 64]; \
    _Pragma("unroll") for (int j = 0; j < 2; ++j) { \
        bfr[NH][0][j] = *(const bf16x8*)&_p[j * 1024 + cA0]; \
        bfr[NH][1][j] = *(const bf16x8*)&_p[j * 1024 + cA1]; } }

#define MFMAQ(MH, NH) { \
    __builtin_amdgcn_s_setprio(1); \
    _Pragma("unroll") for (int i = 0; i < 4; ++i) \
    _Pragma("unroll") for (int j = 0; j < 2; ++j) { \
        f32x4 c = acc[(MH) * 4 + i][(NH) * 2 + j]; \
        c = __builtin_amdgcn_mfma_f32_16x16x32_bf16(af[0][i], bfr[NH][0][j], c, 0, 0, 0); \
        c = __builtin_amdgcn_mfma_f32_16x16x32_bf16(af[1][i], bfr[NH][1][j], c, 0, 0, 0); \
        acc[(MH) * 4 + i][(NH) * 2 + j] = c; } \
    __builtin_amdgcn_s_setprio(0); }

#define WAITV(N) asm volatile("s_waitcnt vmcnt(" #N ")" ::: "memory")
// lgkm drain before EVERY barrier: guarantees this wave's LDS reads are
// complete before it crosses -- closes the DMA-overwrite WAR race.
#define BARL() { asm volatile("s_waitcnt lgkmcnt(0)" ::: "memory"); \
                 asm volatile("s_barrier" ::: "memory"); }

#define ITER(LAST) { \
    /* p1 (0,0) */ ISSUE_A(0, 1, kodd); WAITV(4); BARL(); READ_A(0, 0); READ_B(0, 0); MFMAQ(0, 0); \
    /* p2 (0,1) */ ISSUE_B(0, 1, kodd); WAITV(4); BARL(); READ_B(0, 1); MFMAQ(0, 1); \
    /* p3 (1,1) */ ISSUE_A(1, 1, kodd); WAITV(4); BARL(); READ_A(0, 1); MFMAQ(1, 1); \
    /* p4 (1,0) */ ISSUE_B(1, 1, kodd); WAITV(4); BARL(); MFMAQ(1, 0); \
    /* p5 (0,0) */ if (!(LAST)) { ISSUE_A(0, 0, keven); } WAITV(4); BARL(); READ_A(1, 0); READ_B(1, 0); MFMAQ(0, 0); \
    /* p6 (0,1) */ if (!(LAST)) { ISSUE_B(0, 0, keven); WAITV(4); } else { WAITV(0); } BARL(); READ_B(1, 1); MFMAQ(0, 1); \
    /* p7 (1,1) */ if (!(LAST)) { ISSUE_A(1, 0, keven); WAITV(4); } BARL(); READ_A(1, 1); MFMAQ(1, 1); \
    /* p8 (1,0) */ if (!(LAST)) { ISSUE_B(1, 0, keven); WAITV(4); } BARL(); MFMAQ(1, 0); }

    // prologue: stage tile0 -> buf0 (4 units)
    ISSUE_A(0, 0, 0); ISSUE_B(0, 0, 0); ISSUE_A(1, 0, 0); ISSUE_B(1, 0, 0);

#pragma unroll 1
    for (int it = 0; it < 7; ++it) {
        const int kodd  = it * 128 + 64;   // odd tile (2it+1) k-offset, -> buf1
        const int keven = it * 128 + 128;  // even tile (2it+2) k-offset, -> buf0
        ITER(0);
    }
    {
        const int kodd  = 7 * 128 + 64;    // tile 15 -> buf1
        const int keven = 0;               // unused
        ITER(1);
    }

#undef ITER
#undef WAITV
#undef BARL
#undef MFMAQ
#undef READ_B
#undef READ_A
#undef ISSUE_B
#undef ISSUE_A
#undef GLL16

    // epilogue: C/D layout col=lane&15 (n-side), row=quad*4+reg (m-side)
    const int colb = n0 + wn + fr;
    const int rowb = m0 + wm + quad * 4;
#pragma unroll
    for (int j = 0; j < 4; ++j) {
        int col = colb + j * 16;
        float bv = (OUTMODE == 0 && bias) ? bias[col] : 0.0f;
#pragma unroll
        for (int i = 0; i < 8; ++i) {
            int row = rowb + i * 16;
            if (OUTMODE == 3) {
                if (col < 2048) {       // block-uniform (n0 mult of 256)
#pragma unroll
                    for (int t = 0; t < 4; ++t)
                        ((__bf16*)Cp)[(size_t)(row + t) * 2048 + col] = (__bf16)acc[i][j][t];
                } else {
                    int bb = row / 576;
                    int ml = row - bb * 576;   // ml%4==0, never crosses batch
                    bf16x4 o4;
#pragma unroll
                    for (int t = 0; t < 4; ++t) o4[t] = (__bf16)acc[i][j][t];
                    *(bf16x4*)&((__bf16*)Cp2)[((size_t)bb * 1024 + (col - 2048)) * 576 + ml] = o4;
                }
            } else {
#pragma unroll
                for (int t = 0; t < 4; ++t)
                    ((float*)Cp)[(size_t)(row + t) * N + col] = acc[i][j][t] + bv;
            }
        }
    }
}

// ---------------------------------------------------------------------------
// MFMA gated attention v5r (R1-proven 8-wave structure + posf prefetch).
// Block = (b,h), 512 threads = 8 waves, 2/SIMD. R7 measured 12 waves SLOWER
// (83 vs ~66 us): attn is critical-path-bound, not occupancy-bound.
// NEW: posf (Pp global fragment, L2 ~200-400cyc) is double-buffered one
// kb-step ahead so its latency hides under the mix+MFMA cluster instead of
// sitting in the PV critical path (18 exposed loads/tile before).
// Scratch stride 56 (16B-aligned, 2-way banked). LDS: 73728+73728+14336.
// ---------------------------------------------------------------------------
__global__ __launch_bounds__(512, 2) void attn_mfma3(
    const __bf16* __restrict__ qk, const __bf16* __restrict__ vt,
    const __bf16* __restrict__ Pp, const float* __restrict__ gating,
    __bf16* __restrict__ ao)
{
    __shared__ __bf16 Ks[N_ * HD_];        // [n][d], phys chunk = logical ^ (n&7)
    __shared__ __bf16 Vs[HD_ * N_];        // [d][m], phys = (l&~7)|((l&7)^(d&7))
    __shared__ __bf16 Sc[8 * 16 * 56];     // per-wave scratch [16][56]

    const int bid = blockIdx.x;
    const int h = bid & 15, b = bid >> 4;
    const int tid = threadIdx.x;
    const int lane = tid & 63, wave = tid >> 6;   // 0..7
    const int fr = lane & 15, quad = lane >> 4;

    const __bf16* qbase = qk + (size_t)b * N_ * (2 * D_) + h * HD_;
    const __bf16* kgl   = qbase + D_;
    const __bf16* vgl   = vt + (size_t)(b * H_ + h) * HD_ * N_;

#pragma unroll 3
    for (int it = 0; it < 9; ++it) {
        int s = it * 512 + tid;
        int r = s >> 3, p = s & 7;
        int l = p ^ (r & 7);
        __builtin_amdgcn_global_load_lds(
            (const __attribute__((address_space(1))) void*)(kgl + (size_t)r * (2 * D_) + l * 8),
            (__attribute__((address_space(3))) void*)&Ks[(size_t)(it * 512 + wave * 64) * 8],
            16, 0, 0);
        int d = s / 72, pv = s - d * 72;
        int lv = (pv & ~7) | ((pv & 7) ^ (d & 7));
        __builtin_amdgcn_global_load_lds(
            (const __attribute__((address_space(1))) void*)(vgl + (size_t)d * N_ + lv * 8),
            (__attribute__((address_space(3))) void*)&Vs[(size_t)(it * 512 + wave * 64) * 8],
            16, 0, 0);
    }
    __syncthreads();

    const float g   = 1.f / (1.f + __expf(-gating[h]));
    const float omg = 1.f - g;
    const float kk = 0.125f * LOG2E;

    __bf16* sw = &Sc[wave * 16 * 56];

    for (int tt = wave; tt < 36; tt += 8) {
        const int n0 = tt * 16;

        const __bf16* qp = qbase + (size_t)(n0 + fr) * (2 * D_) + quad * 8;
        bf16x8 qf0 = *(const bf16x8*)qp;
        bf16x8 qf1 = *(const bf16x8*)(qp + 32);

        const __bf16* pprow = Pp + ((size_t)h * N_ + n0 + fr) * N_ + quad * 8;

        f32x4 S[36];
#pragma unroll
        for (int ct = 0; ct < 36; ++ct) {
            int row = ct * 16 + fr;
            int p0 = quad ^ (row & 7);
            int p1 = (4 + quad) ^ (row & 7);
            bf16x8 k0 = *(const bf16x8*)&Ks[row * 64 + p0 * 8];
            bf16x8 k1 = *(const bf16x8*)&Ks[row * 64 + p1 * 8];
            f32x4 a = (f32x4){0.f, 0.f, 0.f, 0.f};
            a = __builtin_amdgcn_mfma_f32_16x16x32_bf16(qf0, k0, a, 0, 0, 0);
            a = __builtin_amdgcn_mfma_f32_16x16x32_bf16(qf1, k1, a, 0, 0, 0);
            S[ct] = a;
        }

        float inv[4];
#pragma unroll
        for (int t = 0; t < 4; ++t) {
            float mt[18];
#pragma unroll
            for (int i = 0; i < 18; ++i) mt[i] = fmaxf(S[i][t], S[i + 18][t]);
#pragma unroll
            for (int i = 0; i < 9; ++i) mt[i] = fmaxf(mt[i], mt[i + 9]);
            float m = fmaxf(fmaxf(fmaxf(mt[0], mt[1]), fmaxf(mt[2], mt[3])),
                            fmaxf(fmaxf(fmaxf(mt[4], mt[5]), fmaxf(mt[6], mt[7])), mt[8]));
            m = fmaxf(m, __shfl_xor(m, 1, 16));
            m = fmaxf(m, __shfl_xor(m, 2, 16));
            m = fmaxf(m, __shfl_xor(m, 4, 16));
            m = fmaxf(m, __shfl_xor(m, 8, 16));
            float km = kk * m;
            float s0 = 0.f, s1 = 0.f, s2 = 0.f, s3 = 0.f;
#pragma unroll
            for (int ct = 0; ct < 36; ++ct) {
                float e = __builtin_amdgcn_exp2f(fmaf(kk, S[ct][t], -km));
                S[ct][t] = e;
                if ((ct & 3) == 0)      s0 += e;
                else if ((ct & 3) == 1) s1 += e;
                else if ((ct & 3) == 2) s2 += e;
                else                    s3 += e;
            }
            float s = (s0 + s1) + (s2 + s3);
            s += __shfl_xor(s, 1, 16);
            s += __shfl_xor(s, 2, 16);
            s += __shfl_xor(s, 4, 16);
            s += __shfl_xor(s, 8, 16);
            inv[t] = omg / s;
        }

        f32x4 O[4];
#pragma unroll
        for (int dt = 0; dt < 4; ++dt) O[dt] = (f32x4){0.f, 0.f, 0.f, 0.f};

        bf16x8 posf = *(const bf16x8*)pprow;   // kb=0 fragment
#pragma unroll
        for (int kb = 0; kb < 18; ++kb) {
            // prefetch next kb's pos fragment BEFORE the mix+MFMA cluster
            bf16x8 posf_nxt = posf;
            if (kb < 17) posf_nxt = *(const bf16x8*)(pprow + (kb + 1) * 32);
#pragma unroll
            for (int ctl = 0; ctl < 2; ++ctl) {
                int ct = 2 * kb + ctl;
#pragma unroll
                for (int t = 0; t < 4; ++t) {
                    float pval = S[ct][t] * inv[t];
                    sw[(quad * 4 + t) * 56 + ctl * 16 + fr] = (__bf16)pval;
                }
            }
            bf16x8 pf = *(const bf16x8*)&sw[fr * 56 + quad * 8];
#pragma unroll
            for (int dt = 0; dt < 4; ++dt) {
                int d = dt * 16 + fr;
                int l = kb * 4 + quad;
                int p = (l & ~7) | ((l & 7) ^ (d & 7));
                bf16x8 vf = *(const bf16x8*)&Vs[d * 576 + p * 8];
                O[dt] = __builtin_amdgcn_mfma_f32_16x16x32_bf16(vf, pf,   O[dt], 0, 0, 0);
                O[dt] = __builtin_amdgcn_mfma_f32_16x16x32_bf16(vf, posf, O[dt], 0, 0, 0);
            }
            posf = posf_nxt;
        }

        asm volatile("s_waitcnt lgkmcnt(0)" ::: "memory");
#pragma unroll
        for (int ps = 0; ps < 2; ++ps) {
#pragma unroll
            for (int dh = 0; dh < 2; ++dh) {
                int dt = 2 * ps + dh;
                bf16x4 o4;
#pragma unroll
                for (int t = 0; t < 4; ++t) o4[t] = (__bf16)O[dt][t];
                *(bf16x4*)&sw[fr * 56 + dh * 16 + quad * 4] = o4;
            }
            asm volatile("s_waitcnt lgkmcnt(0)" ::: "memory");
            {
                int row = lane >> 2;
                int off = (lane & 3) * 8;
                bf16x8 ov = *(const bf16x8*)&sw[row * 56 + off];
                *(bf16x8*)&ao[((size_t)b * N_ + n0 + row) * D_ + h * HD_ + ps * 32 + off] = ov;
            }
            asm volatile("s_waitcnt lgkmcnt(0)" ::: "memory");
        }
    }
}

// ---------------------------------------------------------------------------
extern "C" void kernel_launch(void* const* d_in, const int* in_sizes, int n_in,
                              void* d_out, int out_size, void* d_ws, size_t ws_size,
                              hipStream_t stream)
{
    const float* x      = (const float*)d_in[0];
    const float* W_qk   = (const float*)d_in[1];
    const float* W_v    = (const float*)d_in[2];
    const float* W_proj = (const float*)d_in[3];
    const float* b_proj = (const float*)d_in[4];
    const float* W_pos  = (const float*)d_in[5];
    const float* b_pos  = (const float*)d_in[6];   // unused: cancels in softmax
    const float* gating = (const float*)d_in[7];
    const float* rel    = (const float*)d_in[8];   // unused: computed on the fly
    (void)b_pos; (void)rel;
    float* out = (float*)d_out;

    // workspace carve (~114 MB)
    char* p = (char*)d_ws;
    __bf16* xb    = (__bf16*)p;  p += (size_t)BN_ * D_ * 2;            // 18.9 MB
    __bf16* wqkvt = (__bf16*)p;  p += (size_t)(3 * D_) * D_ * 2;       //  6.3 MB
    __bf16* wpt   = (__bf16*)p;  p += (size_t)D_ * D_ * 2;             //  2.1 MB
    __bf16* qkb   = (__bf16*)p;  p += (size_t)BN_ * (2 * D_) * 2;      // 37.7 MB
    __bf16* vt    = (__bf16*)p;  p += (size_t)BN_ * D_ * 2;            // 18.9 MB [b,h,d,m]
    __bf16* aob   = (__bf16*)p;  p += (size_t)BN_ * D_ * 2;            // 18.9 MB
    __bf16* Pp    = (__bf16*)p;                                        // 10.6 MB [h,n,m]

    // fused prep: cast + 3 transposes + pos softmax (one launch)
    prep<<<12544, 256, 0, stream>>>(x, W_qk, W_v, W_proj, W_pos, gating,
                                    xb, wqkvt, wpt, Pp);
    // fused qk|v GEMM: N=3072; cols<2048 -> qkb, cols>=2048 -> vt (transposed)
    gemm256<3><<<dim3((BN_ / 256) * (3 * D_ / 256)), 512, 0, stream>>>(
        xb, wqkvt, nullptr, qkb, vt, BN_, 3 * D_, 3 * D_ / 256);
    attn_mfma3<<<B_ * H_, 512, 0, stream>>>(qkb, vt, Pp, gating, aob);
    gemm256<0><<<dim3((BN_ / 256) * (D_ / 256)), 512, 0, stream>>>(
        aob, wpt, b_proj, out, nullptr, BN_, D_, D_ / 256);
}

// Round 9
// 271.810 us; speedup vs baseline: 1.1227x; 1.0394x over previous
//
#include <hip/hip_runtime.h>
#include <hip/hip_bf16.h>
#include <math.h>

// Problem constants (ConViT GPSA): B=16, N=576, D=1024, H=16, HD=64
#define B_ 16
#define N_ 576
#define D_ 1024
#define H_ 16
#define HD_ 64
#define BN_ (B_ * N_)   // 9216 rows
#define LOG2E 1.4426950408889634f

typedef __bf16 bf16x8 __attribute__((ext_vector_type(8)));
typedef __bf16 bf16x4 __attribute__((ext_vector_type(4)));
typedef float  f32x4  __attribute__((ext_vector_type(4)));

// ---------------------------------------------------------------------------
// fused prep kernel (one launch instead of 5):
//   region 0 (blocks 0..9215):      cast x fp32 -> xb bf16 (4 elem/thread)
//   region 1 (blocks 9216..10239):  transpose+cast W_qk|W_v -> wqkvt, W_proj -> wpt
//   region 2 (blocks 10240..12543): pos softmax -> Pp[h][n][m] bf16 (4 n/block)
// ---------------------------------------------------------------------------
__global__ __launch_bounds__(256) void prep(
    const float* __restrict__ x, const float* __restrict__ W_qk,
    const float* __restrict__ W_v, const float* __restrict__ W_proj,
    const float* __restrict__ W_pos, const float* __restrict__ gating,
    __bf16* __restrict__ xb, __bf16* __restrict__ wqkvt,
    __bf16* __restrict__ wpt, __bf16* __restrict__ Pp)
{
    __shared__ float t[64][65];
    const int bid = blockIdx.x;
    const int tid = threadIdx.x;

    if (bid < 9216) {
        size_t i = ((size_t)bid * 256 + tid) * 4;
        float4 v = *(const float4*)&x[i];
        bf16x4 o;
        o.x = (__bf16)v.x; o.y = (__bf16)v.y; o.z = (__bf16)v.z; o.w = (__bf16)v.w;
        *(bf16x4*)&xb[i] = o;
    } else if (bid < 10240) {
        int idx = bid - 9216;
        const float* W; __bf16* Wt; int N, bx, by;
        if (idx < 512)      { W = W_qk;   Wt = wqkvt;                          N = 2 * D_; bx = idx & 31; by = idx >> 5; }
        else if (idx < 768) { idx -= 512; W = W_v;    Wt = wqkvt + (size_t)2 * D_ * D_; N = D_; bx = idx & 15; by = idx >> 4; }
        else                { idx -= 768; W = W_proj; Wt = wpt;                N = D_;     bx = idx & 15; by = idx >> 4; }
        const int k0 = by * 64, n0 = bx * 64;
        const int r = tid >> 4, c4 = (tid & 15) << 2;
#pragma unroll
        for (int s = 0; s < 4; ++s) {
            int rr = r + (s << 4);
            float4 w = *(const float4*)&W[(size_t)(k0 + rr) * N + n0 + c4];
            t[rr][c4] = w.x; t[rr][c4 + 1] = w.y; t[rr][c4 + 2] = w.z; t[rr][c4 + 3] = w.w;
        }
        __syncthreads();
#pragma unroll
        for (int s = 0; s < 4; ++s) {
            int rr = r + (s << 4);
            bf16x4 o;
            o.x = (__bf16)t[c4 + 0][rr]; o.y = (__bf16)t[c4 + 1][rr];
            o.z = (__bf16)t[c4 + 2][rr]; o.w = (__bf16)t[c4 + 3][rr];
            *(bf16x4*)&Wt[(size_t)(n0 + rr) * D_ + k0 + c4] = o;
        }
    } else {
        int flat = (bid - 10240) * 4 + (tid >> 6);
        int h = flat / N_, n = flat % N_;
        int lane = tid & 63;
        const float w0 = W_pos[h] * LOG2E, w1 = W_pos[H_ + h] * LOG2E,
                    w2 = W_pos[2 * H_ + h] * LOG2E;
        const float rx = (float)(n % 24), ry = (float)(n / 24);
        float l2[9];
        float mx = -1e30f;
#pragma unroll
        for (int i = 0; i < 9; ++i) {
            int m = lane + (i << 6);
            float cx = (float)(m % 24), cy = (float)(m / 24);
            float dx = cx - rx, dy = cy - ry;
            float l = fmaf(w2, fmaf(dx, dx, dy * dy), fmaf(w0, dx, w1 * dy));
            l2[i] = l;
            mx = fmaxf(mx, l);
        }
#pragma unroll
        for (int off = 32; off; off >>= 1) mx = fmaxf(mx, __shfl_xor(mx, off, 64));
        float sum = 0.f;
#pragma unroll
        for (int i = 0; i < 9; ++i) sum += __builtin_amdgcn_exp2f(l2[i] - mx);
#pragma unroll
        for (int off = 32; off; off >>= 1) sum += __shfl_xor(sum, off, 64);
        float g = 1.f / (1.f + __expf(-gating[h]));
        float c = __log2f(g) - mx - __log2f(sum);
        __bf16* row = Pp + (size_t)(h * N_ + n) * N_;
#pragma unroll
        for (int i = 0; i < 9; ++i)
            row[(i << 6) + lane] = (__bf16)__builtin_amdgcn_exp2f(l2[i] + c);
    }
}

// ---------------------------------------------------------------------------
// 256x256 4-phase deep-pipelined bf16 MFMA GEMM, K=1024.
// C[M,N] = A[M,K] @ Bt[N,K]^T (+bias). 512 thr = 8 waves (2M x 4N), per-wave
// 128x64 out. LDS 2-buf x (A 256x64 + B 256x64) = 128 KiB, chunk-XOR swizzle
// (phys16B = logical ^ (row&7)), pre-swizzled global src + linear gll dest.
//
// R9: 4 phases per 2 K-tiles (was 8). Per block: 64 phases -> 32 barriers.
// Arithmetic: per-phase fixed cost (barrier skew + lgkm drain + ds_read ramp)
// measured ~860 cyc vs ~620 cyc MFMA at 8-phase -> halve barrier count to
// amortize over 2x MFMA (32/phase). Each phase issues 2 stage-units (4 loads)
// and waits a counted vmcnt derived from the in-order retirement ledger:
//   P1 needs prevP3{A0,B0}+prevP4-first{B1}: newer = A1(2)+own(4) -> vmcnt(6)
//   P2 needs prevP4-last{A1}:                newer = own(4)+P1(4) -> vmcnt(8)
//   P3/P4 symmetric on the kodd units; tail 2/0.
// WAR: DMA in phase X is region-disjoint from phase X-1's reads (A0B0 vs A1);
// each buffer's last read is >=2 barriers before its overwrite; lgkm drain
// before every barrier retires reads before the wave crosses.
// Stage units: A0 = A rows {0-63,128-191}, A1 = +64;
//              B0 = Bt rows {0-31,64-95,128-159,192-223}, B1 = +32.
// OUTMODE: 0 = fp32 C[M,N]+bias; 3 = fused qk|v split (see launch).
// ---------------------------------------------------------------------------
template<int OUTMODE>
__global__ __launch_bounds__(512, 2) void gemm256(
    const __bf16* __restrict__ A, const __bf16* __restrict__ Bt,
    const float* __restrict__ bias, void* __restrict__ Cp, void* __restrict__ Cp2,
    int M, int N, int nbn)
{
    __shared__ __bf16 As[2][256 * 64];
    __shared__ __bf16 Bs[2][256 * 64];

    const int tid = threadIdx.x;
    const int lane = tid & 63, wave = tid >> 6;
    const int fr = lane & 15, quad = lane >> 4;

    // XCD-aware block swizzle (grid % 8 == 0 for both shapes)
    const int nwg = gridDim.x;
    const int wg = ((int)blockIdx.x & 7) * (nwg >> 3) + ((int)blockIdx.x >> 3);
    const int m0 = (wg / nbn) * 256;
    const int n0 = (wg % nbn) * 256;

    const int wm = (wave >> 2) * 128;
    const int wn = (wave & 3) * 64;

    // --- staging invariants: per-rep global offsets (pre-swizzled) + LDS dests
    int offA[2], offB[2], dA[2], dB[2];
#pragma unroll
    for (int r = 0; r < 2; ++r) {
        int rl = r * 64 + (tid >> 3);          // 16B-slot row index within unit
        int pc = tid & 7;                      // phys chunk
        int l  = pc ^ (rl & 7);                // logical chunk (pre-swizzle)
        int rowA = (rl & 63) | ((rl & 64) << 1);
        int rowB = (rl & 31) + ((rl >> 5) << 6);
        offA[r] = (m0 + rowA) * 1024 + l * 8;
        offB[r] = (n0 + rowB) * 1024 + l * 8;
        int rlb = r * 64 + wave * 8;           // wave-uniform dest base
        int rowAb = (rlb & 63) | ((rlb & 64) << 1);
        int rowBb = (rlb & 31) + ((rlb >> 5) << 6);
        dA[r] = rowAb * 64;
        dB[r] = rowBb * 64;
    }

    const int cA0 = (quad ^ (fr & 7)) * 8;         // kslice0 chunk (swizzled)
    const int cA1 = ((4 + quad) ^ (fr & 7)) * 8;   // kslice1 chunk

    f32x4 acc[8][4];
#pragma unroll
    for (int i = 0; i < 8; ++i)
#pragma unroll
        for (int j = 0; j < 4; ++j)
            acc[i][j] = (f32x4){0.f, 0.f, 0.f, 0.f};

    bf16x8 af[2][4];        // current M-half A frags [kslice][i]
    bf16x8 bfr[2][2][2];    // whole-tile B frags [nhalf][kslice][j]

#define GLL16(src, dst) __builtin_amdgcn_global_load_lds( \
    (const __attribute__((address_space(1))) void*)(src), \
    (__attribute__((address_space(3))) void*)(dst), 16, 0, 0)

#define ISSUE_A(U, BUF, KOFF) { \
    GLL16(A + offA[0] + (U) * 65536 + (KOFF), &As[BUF][dA[0] + (U) * 4096]); \
    GLL16(A + offA[1] + (U) * 65536 + (KOFF), &As[BUF][dA[1] + (U) * 4096]); }
#define ISSUE_B(U, BUF, KOFF) { \
    GLL16(Bt + offB[0] + (U) * 32768 + (KOFF), &Bs[BUF][dB[0] + (U) * 2048]); \
    GLL16(Bt + offB[1] + (U) * 32768 + (KOFF), &Bs[BUF][dB[1] + (U) * 2048]); }

#define READ_A(BUF, MH) { \
    const __bf16* _p = &As[BUF][(wm + (MH) * 64 + fr) * 64]; \
    _Pragma("unroll") for (int i = 0; i < 4; ++i) { \
        af[0][i] = *(const bf16x8*)&_p[i * 1024 + cA0]; \
        af[1][i] = *(const bf16x8*)&_p[i * 1024 + cA1]; } }

#define READ_B(BUF, NH) { \
    const __bf16* _p = &Bs[BUF][(wn + (NH) * 32 + fr) * 64]; \
    _Pragma("unroll") for (int j = 0; j < 2; ++j) { \
        bfr[NH][0][j] = *(const bf16x8*)&_p[j * 1024 + cA0]; \
        bfr[NH][1][j] = *(const bf16x8*)&_p[j * 1024 + cA1]; } }

#define MFMAQ(MH, NH) { \
    __builtin_amdgcn_s_setprio(1); \
    _Pragma("unroll") for (int i = 0; i < 4; ++i) \
    _Pragma("unroll") for (int j = 0; j < 2; ++j) { \
        f32x4 c = acc[(MH) * 4 + i][(NH) * 2 + j]; \
        c = __builtin_amdgcn_mfma_f32_16x16x32_bf16(af[0][i], bfr[NH][0][j], c, 0, 0, 0); \
        c = __builtin_amdgcn_mfma_f32_16x16x32_bf16(af[1][i], bfr[NH][1][j], c, 0, 0, 0); \
        acc[(MH) * 4 + i][(NH) * 2 + j] = c; } \
    __builtin_amdgcn_s_setprio(0); }

#define WAITV(N) asm volatile("s_waitcnt vmcnt(" #N ")" ::: "memory")
// lgkm drain before EVERY barrier: this wave's LDS reads complete before it
// crosses -- closes the DMA-overwrite WAR race.
#define BARL() { asm volatile("s_waitcnt lgkmcnt(0)" ::: "memory"); \
                 asm volatile("s_barrier" ::: "memory"); }

#define ITER4(LAST) { \
  /*P1: buf0 MH0xN01*/ ISSUE_A(0, 1, kodd); ISSUE_B(0, 1, kodd); WAITV(6); BARL(); \
        READ_A(0, 0); READ_B(0, 0); READ_B(0, 1); MFMAQ(0, 0); MFMAQ(0, 1); \
  /*P2: buf0 MH1xN01*/ ISSUE_B(1, 1, kodd); ISSUE_A(1, 1, kodd); WAITV(8); BARL(); \
        READ_A(0, 1); MFMAQ(1, 0); MFMAQ(1, 1); \
  /*P3: buf1 MH0xN01*/ if (!(LAST)) { ISSUE_A(0, 0, keven); ISSUE_B(0, 0, keven); WAITV(6); } \
                       else { WAITV(2); } BARL(); \
        READ_A(1, 0); READ_B(1, 0); READ_B(1, 1); MFMAQ(0, 0); MFMAQ(0, 1); \
  /*P4: buf1 MH1xN01*/ if (!(LAST)) { ISSUE_B(1, 0, keven); ISSUE_A(1, 0, keven); WAITV(8); } \
                       else { WAITV(0); } BARL(); \
        READ_A(1, 1); MFMAQ(1, 0); MFMAQ(1, 1); }

    // prologue: stage tile0 -> buf0 in the P3/P4 pattern order A0,B0,B1,A1
    ISSUE_A(0, 0, 0); ISSUE_B(0, 0, 0); ISSUE_B(1, 0, 0); ISSUE_A(1, 0, 0);

#pragma unroll 1
    for (int it = 0; it < 7; ++it) {
        const int kodd  = it * 128 + 64;   // odd tile (2it+1) k-offset, -> buf1
        const int keven = it * 128 + 128;  // even tile (2it+2) k-offset, -> buf0
        ITER4(0);
    }
    {
        const int kodd  = 7 * 128 + 64;    // tile 15 -> buf1
        const int keven = 0;               // unused
        ITER4(1);
    }

#undef ITER4
#undef WAITV
#undef BARL
#undef MFMAQ
#undef READ_B
#undef READ_A
#undef ISSUE_B
#undef ISSUE_A
#undef GLL16

    // epilogue: C/D layout col=lane&15 (n-side), row=quad*4+reg (m-side)
    const int colb = n0 + wn + fr;
    const int rowb = m0 + wm + quad * 4;
#pragma unroll
    for (int j = 0; j < 4; ++j) {
        int col = colb + j * 16;
        float bv = (OUTMODE == 0 && bias) ? bias[col] : 0.0f;
#pragma unroll
        for (int i = 0; i < 8; ++i) {
            int row = rowb + i * 16;
            if (OUTMODE == 3) {
                if (col < 2048) {       // block-uniform (n0 mult of 256)
#pragma unroll
                    for (int t = 0; t < 4; ++t)
                        ((__bf16*)Cp)[(size_t)(row + t) * 2048 + col] = (__bf16)acc[i][j][t];
                } else {
                    int bb = row / 576;
                    int ml = row - bb * 576;   // ml%4==0, never crosses batch
                    bf16x4 o4;
#pragma unroll
                    for (int t = 0; t < 4; ++t) o4[t] = (__bf16)acc[i][j][t];
                    *(bf16x4*)&((__bf16*)Cp2)[((size_t)bb * 1024 + (col - 2048)) * 576 + ml] = o4;
                }
            } else {
#pragma unroll
                for (int t = 0; t < 4; ++t)
                    ((float*)Cp)[(size_t)(row + t) * N + col] = acc[i][j][t] + bv;
            }
        }
    }
}

// ---------------------------------------------------------------------------
// MFMA gated attention v5r (R1-proven 8-wave structure + posf prefetch).
// Block = (b,h), 512 threads = 8 waves, 2/SIMD (12 waves measured SLOWER, R7:
// critical-path-bound, not occupancy-bound). posf double-buffered one kb ahead.
// Scratch stride 56 (16B-aligned, 2-way banked). LDS: 73728+73728+14336.
// ---------------------------------------------------------------------------
__global__ __launch_bounds__(512, 2) void attn_mfma3(
    const __bf16* __restrict__ qk, const __bf16* __restrict__ vt,
    const __bf16* __restrict__ Pp, const float* __restrict__ gating,
    __bf16* __restrict__ ao)
{
    __shared__ __bf16 Ks[N_ * HD_];        // [n][d], phys chunk = logical ^ (n&7)
    __shared__ __bf16 Vs[HD_ * N_];        // [d][m], phys = (l&~7)|((l&7)^(d&7))
    __shared__ __bf16 Sc[8 * 16 * 56];     // per-wave scratch [16][56]

    const int bid = blockIdx.x;
    const int h = bid & 15, b = bid >> 4;
    const int tid = threadIdx.x;
    const int lane = tid & 63, wave = tid >> 6;   // 0..7
    const int fr = lane & 15, quad = lane >> 4;

    const __bf16* qbase = qk + (size_t)b * N_ * (2 * D_) + h * HD_;
    const __bf16* kgl   = qbase + D_;
    const __bf16* vgl   = vt + (size_t)(b * H_ + h) * HD_ * N_;

#pragma unroll 3
    for (int it = 0; it < 9; ++it) {
        int s = it * 512 + tid;
        int r = s >> 3, p = s & 7;
        int l = p ^ (r & 7);
        __builtin_amdgcn_global_load_lds(
            (const __attribute__((address_space(1))) void*)(kgl + (size_t)r * (2 * D_) + l * 8),
            (__attribute__((address_space(3))) void*)&Ks[(size_t)(it * 512 + wave * 64) * 8],
            16, 0, 0);
        int d = s / 72, pv = s - d * 72;
        int lv = (pv & ~7) | ((pv & 7) ^ (d & 7));
        __builtin_amdgcn_global_load_lds(
            (const __attribute__((address_space(1))) void*)(vgl + (size_t)d * N_ + lv * 8),
            (__attribute__((address_space(3))) void*)&Vs[(size_t)(it * 512 + wave * 64) * 8],
            16, 0, 0);
    }
    __syncthreads();

    const float g   = 1.f / (1.f + __expf(-gating[h]));
    const float omg = 1.f - g;
    const float kk = 0.125f * LOG2E;

    __bf16* sw = &Sc[wave * 16 * 56];

    for (int tt = wave; tt < 36; tt += 8) {
        const int n0 = tt * 16;

        const __bf16* qp = qbase + (size_t)(n0 + fr) * (2 * D_) + quad * 8;
        bf16x8 qf0 = *(const bf16x8*)qp;
        bf16x8 qf1 = *(const bf16x8*)(qp + 32);

        const __bf16* pprow = Pp + ((size_t)h * N_ + n0 + fr) * N_ + quad * 8;

        f32x4 S[36];
#pragma unroll
        for (int ct = 0; ct < 36; ++ct) {
            int row = ct * 16 + fr;
            int p0 = quad ^ (row & 7);
            int p1 = (4 + quad) ^ (row & 7);
            bf16x8 k0 = *(const bf16x8*)&Ks[row * 64 + p0 * 8];
            bf16x8 k1 = *(const bf16x8*)&Ks[row * 64 + p1 * 8];
            f32x4 a = (f32x4){0.f, 0.f, 0.f, 0.f};
            a = __builtin_amdgcn_mfma_f32_16x16x32_bf16(qf0, k0, a, 0, 0, 0);
            a = __builtin_amdgcn_mfma_f32_16x16x32_bf16(qf1, k1, a, 0, 0, 0);
            S[ct] = a;
        }

        float inv[4];
#pragma unroll
        for (int t = 0; t < 4; ++t) {
            float mt[18];
#pragma unroll
            for (int i = 0; i < 18; ++i) mt[i] = fmaxf(S[i][t], S[i + 18][t]);
#pragma unroll
            for (int i = 0; i < 9; ++i) mt[i] = fmaxf(mt[i], mt[i + 9]);
            float m = fmaxf(fmaxf(fmaxf(mt[0], mt[1]), fmaxf(mt[2], mt[3])),
                            fmaxf(fmaxf(fmaxf(mt[4], mt[5]), fmaxf(mt[6], mt[7])), mt[8]));
            m = fmaxf(m, __shfl_xor(m, 1, 16));
            m = fmaxf(m, __shfl_xor(m, 2, 16));
            m = fmaxf(m, __shfl_xor(m, 4, 16));
            m = fmaxf(m, __shfl_xor(m, 8, 16));
            float km = kk * m;
            float s0 = 0.f, s1 = 0.f, s2 = 0.f, s3 = 0.f;
#pragma unroll
            for (int ct = 0; ct < 36; ++ct) {
                float e = __builtin_amdgcn_exp2f(fmaf(kk, S[ct][t], -km));
                S[ct][t] = e;
                if ((ct & 3) == 0)      s0 += e;
                else if ((ct & 3) == 1) s1 += e;
                else if ((ct & 3) == 2) s2 += e;
                else                    s3 += e;
            }
            float s = (s0 + s1) + (s2 + s3);
            s += __shfl_xor(s, 1, 16);
            s += __shfl_xor(s, 2, 16);
            s += __shfl_xor(s, 4, 16);
            s += __shfl_xor(s, 8, 16);
            inv[t] = omg / s;
        }

        f32x4 O[4];
#pragma unroll
        for (int dt = 0; dt < 4; ++dt) O[dt] = (f32x4){0.f, 0.f, 0.f, 0.f};

        bf16x8 posf = *(const bf16x8*)pprow;   // kb=0 fragment
#pragma unroll
        for (int kb = 0; kb < 18; ++kb) {
            bf16x8 posf_nxt = posf;
            if (kb < 17) posf_nxt = *(const bf16x8*)(pprow + (kb + 1) * 32);
#pragma unroll
            for (int ctl = 0; ctl < 2; ++ctl) {
                int ct = 2 * kb + ctl;
#pragma unroll
                for (int t = 0; t < 4; ++t) {
                    float pval = S[ct][t] * inv[t];
                    sw[(quad * 4 + t) * 56 + ctl * 16 + fr] = (__bf16)pval;
                }
            }
            bf16x8 pf = *(const bf16x8*)&sw[fr * 56 + quad * 8];
#pragma unroll
            for (int dt = 0; dt < 4; ++dt) {
                int d = dt * 16 + fr;
                int l = kb * 4 + quad;
                int p = (l & ~7) | ((l & 7) ^ (d & 7));
                bf16x8 vf = *(const bf16x8*)&Vs[d * 576 + p * 8];
                O[dt] = __builtin_amdgcn_mfma_f32_16x16x32_bf16(vf, pf,   O[dt], 0, 0, 0);
                O[dt] = __builtin_amdgcn_mfma_f32_16x16x32_bf16(vf, posf, O[dt], 0, 0, 0);
            }
            posf = posf_nxt;
        }

        asm volatile("s_waitcnt lgkmcnt(0)" ::: "memory");
#pragma unroll
        for (int ps = 0; ps < 2; ++ps) {
#pragma unroll
            for (int dh = 0; dh < 2; ++dh) {
                int dt = 2 * ps + dh;
                bf16x4 o4;
#pragma unroll
                for (int t = 0; t < 4; ++t) o4[t] = (__bf16)O[dt][t];
                *(bf16x4*)&sw[fr * 56 + dh * 16 + quad * 4] = o4;
            }
            asm volatile("s_waitcnt lgkmcnt(0)" ::: "memory");
            {
                int row = lane >> 2;
                int off = (lane & 3) * 8;
                bf16x8 ov = *(const bf16x8*)&sw[row * 56 + off];
                *(bf16x8*)&ao[((size_t)b * N_ + n0 + row) * D_ + h * HD_ + ps * 32 + off] = ov;
            }
            asm volatile("s_waitcnt lgkmcnt(0)" ::: "memory");
        }
    }
}

// ---------------------------------------------------------------------------
extern "C" void kernel_launch(void* const* d_in, const int* in_sizes, int n_in,
                              void* d_out, int out_size, void* d_ws, size_t ws_size,
                              hipStream_t stream)
{
    const float* x      = (const float*)d_in[0];
    const float* W_qk   = (const float*)d_in[1];
    const float* W_v    = (const float*)d_in[2];
    const float* W_proj = (const float*)d_in[3];
    const float* b_proj = (const float*)d_in[4];
    const float* W_pos  = (const float*)d_in[5];
    const float* b_pos  = (const float*)d_in[6];   // unused: cancels in softmax
    const float* gating = (const float*)d_in[7];
    const float* rel    = (const float*)d_in[8];   // unused: computed on the fly
    (void)b_pos; (void)rel;
    float* out = (float*)d_out;

    // workspace carve (~114 MB)
    char* p = (char*)d_ws;
    __bf16* xb    = (__bf16*)p;  p += (size_t)BN_ * D_ * 2;            // 18.9 MB
    __bf16* wqkvt = (__bf16*)p;  p += (size_t)(3 * D_) * D_ * 2;       //  6.3 MB
    __bf16* wpt   = (__bf16*)p;  p += (size_t)D_ * D_ * 2;             //  2.1 MB
    __bf16* qkb   = (__bf16*)p;  p += (size_t)BN_ * (2 * D_) * 2;      // 37.7 MB
    __bf16* vt    = (__bf16*)p;  p += (size_t)BN_ * D_ * 2;            // 18.9 MB [b,h,d,m]
    __bf16* aob   = (__bf16*)p;  p += (size_t)BN_ * D_ * 2;            // 18.9 MB
    __bf16* Pp    = (__bf16*)p;                                        // 10.6 MB [h,n,m]

    // fused prep: cast + 3 transposes + pos softmax (one launch)
    prep<<<12544, 256, 0, stream>>>(x, W_qk, W_v, W_proj, W_pos, gating,
                                    xb, wqkvt, wpt, Pp);
    // fused qk|v GEMM: N=3072; cols<2048 -> qkb, cols>=2048 -> vt (transposed)
    gemm256<3><<<dim3((BN_ / 256) * (3 * D_ / 256)), 512, 0, stream>>>(
        xb, wqkvt, nullptr, qkb, vt, BN_, 3 * D_, 3 * D_ / 256);
    attn_mfma3<<<B_ * H_, 512, 0, stream>>>(qkb, vt, Pp, gating, aob);
    gemm256<0><<<dim3((BN_ / 256) * (D_ / 256)), 512, 0, stream>>>(
        aob, wpt, b_proj, out, nullptr, BN_, D_, D_ / 256);
}